// Round 2
// baseline (64967.419 us; speedup 1.0000x reference)
//
#include <hip/hip_runtime.h>
#include <hip/hip_cooperative_groups.h>
#include <math.h>

namespace cg = cooperative_groups;

#define BB_  64
#define TT_  512
#define DD_  1024
#define HH_  1024

// ===========================================================================
// bf16 split helpers: hi = bf16_rte(f), rem = f - float(hi) (exact)
// ===========================================================================
__device__ __forceinline__ unsigned short bf_hi(float f, float& rem) {
    unsigned u = __float_as_uint(f);
    unsigned r = (u + 0x7FFFu + ((u >> 16) & 1u)) >> 16;
    rem = f - __uint_as_float(r << 16);
    return (unsigned short)r;
}

// Pack x [32768][1024] f32 -> Ap [32768][3072] bf16 = [xh | xh | xl]
__global__ __launch_bounds__(256)
void pack_x(const float* __restrict__ x, unsigned short* __restrict__ Ap)
{
    size_t i = (size_t)blockIdx.x * 256 + threadIdx.x;   // float4 idx, 8M total
    float4 v = ((const float4*)x)[i];
    size_t e = i * 4;
    size_t m = e >> 10;
    int k = (int)(e & 1023);
    float r0, r1, r2, r3, d;
    ushort4 hi, lo;
    hi.x = bf_hi(v.x, r0); hi.y = bf_hi(v.y, r1);
    hi.z = bf_hi(v.z, r2); hi.w = bf_hi(v.w, r3);
    lo.x = bf_hi(r0, d);   lo.y = bf_hi(r1, d);
    lo.z = bf_hi(r2, d);   lo.w = bf_hi(r3, d);
    unsigned short* base = Ap + m * 3072 + k;
    *(ushort4*)(base)        = hi;
    *(ushort4*)(base + 1024) = hi;
    *(ushort4*)(base + 2048) = lo;
}

// Pack W_ih [4096][1024] f32 -> Bp [4096][3072] bf16 = [Wh | Wl | Wh]
__global__ __launch_bounds__(256)
void pack_w(const float* __restrict__ w, unsigned short* __restrict__ Bp)
{
    size_t i = (size_t)blockIdx.x * 256 + threadIdx.x;   // float4 idx, 1M total
    float4 v = ((const float4*)w)[i];
    size_t e = i * 4;
    size_t n = e >> 10;
    int k = (int)(e & 1023);
    float r0, r1, r2, r3, d;
    ushort4 hi, lo;
    hi.x = bf_hi(v.x, r0); hi.y = bf_hi(v.y, r1);
    hi.z = bf_hi(v.z, r2); hi.w = bf_hi(v.w, r3);
    lo.x = bf_hi(r0, d);   lo.y = bf_hi(r1, d);
    lo.z = bf_hi(r2, d);   lo.w = bf_hi(r3, d);
    unsigned short* base = Bp + n * 3072 + k;
    *(ushort4*)(base)        = hi;
    *(ushort4*)(base + 1024) = lo;
    *(ushort4*)(base + 2048) = hi;
}

// ===========================================================================
// bf16 MFMA GEMM:  C[m][n] = sum_k A[m][k]*B[n][k],  A[32768][3072],
// B[4096][3072], C f32 [32768][4096].  128x128 tile, BK=64, 4 waves,
// XOR-swizzled LDS (chunk ^= row&7) to kill the stride-128B bank conflict.
// grid: x = n-tile (32), y = m-tile (256)  -> x-fastest = A-panel reuse in L2.
// ===========================================================================
typedef short bf16frag __attribute__((ext_vector_type(8)));
typedef float f32x4 __attribute__((ext_vector_type(4)));

__global__ __launch_bounds__(256)
void gemm_bf16x3(const unsigned short* __restrict__ A,
                 const unsigned short* __restrict__ B,
                 float* __restrict__ C)
{
    __shared__ unsigned short As[128 * 64];   // [row][k] bf16, swizzled chunks
    __shared__ unsigned short Bs[128 * 64];
    const int tid = threadIdx.x;
    const size_t m0 = (size_t)blockIdx.y * 128;
    const size_t n0 = (size_t)blockIdx.x * 128;
    const int wave = tid >> 6, lane = tid & 63;
    const int wr = wave >> 1, wc = wave & 1;

    f32x4 acc[4][4];
#pragma unroll
    for (int i = 0; i < 4; ++i)
#pragma unroll
        for (int j = 0; j < 4; ++j)
#pragma unroll
            for (int r = 0; r < 4; ++r) acc[i][j][r] = 0.f;

    for (int k0 = 0; k0 < 3072; k0 += 64) {
        uint4 ra[4], rb[4];
#pragma unroll
        for (int c = 0; c < 4; ++c) {
            int chunk = tid + c * 256;          // 0..1023 = [row 128][kc 8]
            int row = chunk >> 3, kc = chunk & 7;
            ra[c] = *(const uint4*)(A + (m0 + row) * 3072 + k0 + kc * 8);
            rb[c] = *(const uint4*)(B + (n0 + row) * 3072 + k0 + kc * 8);
        }
        __syncthreads();
#pragma unroll
        for (int c = 0; c < 4; ++c) {
            int chunk = tid + c * 256;
            int row = chunk >> 3, kc = chunk & 7;
            int sc = kc ^ (row & 7);
            *(uint4*)&As[row * 64 + sc * 8] = ra[c];
            *(uint4*)&Bs[row * 64 + sc * 8] = rb[c];
        }
        __syncthreads();
#pragma unroll
        for (int kk = 0; kk < 64; kk += 32) {
            bf16frag af[4], bfv[4];
            const int ch = (kk >> 3) + (lane >> 4);
#pragma unroll
            for (int i = 0; i < 4; ++i) {
                int arow = wr * 64 + i * 16 + (lane & 15);
                af[i] = *(const bf16frag*)&As[arow * 64 + (ch ^ (arow & 7)) * 8];
                int brow = wc * 64 + i * 16 + (lane & 15);
                bfv[i] = *(const bf16frag*)&Bs[brow * 64 + (ch ^ (brow & 7)) * 8];
            }
#pragma unroll
            for (int i = 0; i < 4; ++i)
#pragma unroll
                for (int j = 0; j < 4; ++j)
                    acc[i][j] = __builtin_amdgcn_mfma_f32_16x16x32_bf16(
                        af[i], bfv[j], acc[i][j], 0, 0, 0);
        }
        __syncthreads();
    }
    // D: col = lane&15, row = (lane>>4)*4 + r   (m from A-frag, n from B-frag)
#pragma unroll
    for (int i = 0; i < 4; ++i) {
        size_t mrow = m0 + wr * 64 + i * 16 + (lane >> 4) * 4;
#pragma unroll
        for (int j = 0; j < 4; ++j) {
            size_t ncol = n0 + wc * 64 + j * 16 + (lane & 15);
            float* cp = C + mrow * 4096 + ncol;
            cp[0]        = acc[i][j][0];
            cp[4096]     = acc[i][j][1];
            cp[2 * 4096] = acc[i][j][2];
            cp[3 * 4096] = acc[i][j][3];
        }
    }
}

// ===========================================================================
// fp32 fallback GEMM (proven last round) — used only if ws too small
// ===========================================================================
__global__ __launch_bounds__(256)
void gemm_nt_f32(const float* __restrict__ A, long lda, int M,
                 const float* __restrict__ Bw,
                 float* __restrict__ C, long ldc)
{
    __shared__ __align__(16) float As[16][132];
    __shared__ __align__(16) float Bs[16][132];
    const int tid = threadIdx.x;
    const long m0 = (long)blockIdx.x * 128;
    const long n0 = (long)blockIdx.y * 128;
    const int tx = tid & 15, ty = tid >> 4;
    const int sr = tid >> 2, sc = (tid & 3) << 2;
    float acc[8][8];
#pragma unroll
    for (int i = 0; i < 8; ++i)
#pragma unroll
        for (int j = 0; j < 8; ++j) acc[i][j] = 0.f;
    for (int k0 = 0; k0 < 1024; k0 += 16) {
#pragma unroll
        for (int rr = 0; rr < 2; ++rr) {
            long arow = m0 + sr + rr * 64;
            float4 v = make_float4(0.f, 0.f, 0.f, 0.f);
            if ((int)arow < M) v = *(const float4*)(A + arow * lda + k0 + sc);
            As[sc + 0][sr + rr * 64] = v.x; As[sc + 1][sr + rr * 64] = v.y;
            As[sc + 2][sr + rr * 64] = v.z; As[sc + 3][sr + rr * 64] = v.w;
            long bcol = n0 + sr + rr * 64;
            float4 w = *(const float4*)(Bw + bcol * 1024 + k0 + sc);
            Bs[sc + 0][sr + rr * 64] = w.x; Bs[sc + 1][sr + rr * 64] = w.y;
            Bs[sc + 2][sr + rr * 64] = w.z; Bs[sc + 3][sr + rr * 64] = w.w;
        }
        __syncthreads();
#pragma unroll
        for (int k = 0; k < 16; ++k) {
            float4 a0 = *(const float4*)&As[k][ty * 8];
            float4 a1 = *(const float4*)&As[k][ty * 8 + 4];
            float4 b0 = *(const float4*)&Bs[k][tx * 8];
            float4 b1 = *(const float4*)&Bs[k][tx * 8 + 4];
            float av[8] = {a0.x, a0.y, a0.z, a0.w, a1.x, a1.y, a1.z, a1.w};
            float bv[8] = {b0.x, b0.y, b0.z, b0.w, b1.x, b1.y, b1.z, b1.w};
#pragma unroll
            for (int i = 0; i < 8; ++i)
#pragma unroll
                for (int j = 0; j < 8; ++j) acc[i][j] += av[i] * bv[j];
        }
        __syncthreads();
    }
#pragma unroll
    for (int i = 0; i < 8; ++i) {
        long row = m0 + ty * 8 + i;
        if ((int)row < M) {
            *(float4*)(C + row * ldc + n0 + tx * 8) =
                make_float4(acc[i][0], acc[i][1], acc[i][2], acc[i][3]);
            *(float4*)(C + row * ldc + n0 + tx * 8 + 4) =
                make_float4(acc[i][4], acc[i][5], acc[i][6], acc[i][7]);
        }
    }
}

// ===========================================================================
// Persistent recurrent kernel: 256 blocks x 1024 threads (cooperative).
// Block owns h-cols h0..h0+3; W slice (12 gate rows) lives in LDS for all
// 512 steps; h double-buffered in ws (transposed float4-packed h4[k4][b]);
// c and running h live in registers of threads 0..255.
// ===========================================================================
__global__ __launch_bounds__(1024, 4)
void lstm_persist(const float* __restrict__ Whh,
                  const float* __restrict__ gi,      // [(b*512+t)][4096]
                  const int* __restrict__ lengths,
                  float* __restrict__ hbuf,          // 2 * 65536 floats
                  float* __restrict__ seq,           // [64][512][1024]
                  float* __restrict__ hfin)          // [64][1024]
{
    __shared__ float Ws[12][1024];       // rows: hl*3 + {0:i,1:g,2:o}
    __shared__ float red[16][12][66];

    const int tid  = threadIdx.x;
    const int h0   = blockIdx.x << 2;
    const int wave = tid >> 6;
    const int lane = tid & 63;           // = batch in phase A
    const int cb   = tid >> 2;           // batch in phase B
    const int hl   = tid & 3;

    // ---- load W slice into LDS (once) ----
    for (int i = tid; i < 12 * 256; i += 1024) {
        int r = i >> 8, k4 = i & 255;
        int rhl = r / 3, q = r - rhl * 3;
        int grow = (q == 0) ? (h0 + rhl) : (q == 1) ? (2048 + h0 + rhl)
                                                    : (3072 + h0 + rhl);
        *(float4*)&Ws[r][k4 * 4] = *(const float4*)(Whh + (size_t)grow * 1024 + k4 * 4);
    }
    // ---- zero own slice of h buffer 0 ----
    if (tid < 256) hbuf[blockIdx.x * 256 + tid] = 0.f;

    float h_reg = 0.f, c_reg = 0.f;
    int len_b = 0;
    size_t gi_base = 0;
    if (tid < 256) {
        len_b = lengths[cb];
        gi_base = ((size_t)cb * TT_) * 4096 + h0 + hl;
    }

    cg::grid_group grid = cg::this_grid();
    __threadfence();
    grid.sync();

    for (int t = 0; t < TT_; ++t) {
        const float4* hin = (const float4*)(hbuf + (t & 1) * 65536);

        // prefetch gi for the cell phase (hidden under the GEMM phase)
        float gv0 = 0.f, gv1 = 0.f, gv2 = 0.f, gv3 = 0.f;
        if (tid < 256) {
            const float* gp = gi + gi_base + (size_t)t * 4096;
            gv0 = gp[0]; gv1 = gp[1024]; gv2 = gp[2048]; gv3 = gp[3072];
        }

        // ---- phase A: partial dots over this wave's k-slice ----
        float acc[12];
#pragma unroll
        for (int r = 0; r < 12; ++r) acc[r] = 0.f;
        const int k4b = wave * 16;
        const float4* hq = hin + (size_t)k4b * 64 + lane;
        for (int k4 = 0; k4 < 16; ++k4) {
            float4 hv = hq[(size_t)k4 * 64];
            const int kc = (k4b + k4) * 4;
#pragma unroll
            for (int r = 0; r < 12; ++r) {
                float4 wv = *(const float4*)&Ws[r][kc];
                acc[r] += hv.x * wv.x + hv.y * wv.y + hv.z * wv.z + hv.w * wv.w;
            }
        }
#pragma unroll
        for (int r = 0; r < 12; ++r) red[wave][r][lane] = acc[r];
        __syncthreads();

        // ---- phase B: reduce + cell math (threads 0..255) ----
        if (tid < 256) {
            float h_i = 0.f, h_g = 0.f, h_o = 0.f;
#pragma unroll
            for (int w = 0; w < 16; ++w) {
                h_i += red[w][hl * 3 + 0][cb];
                h_g += red[w][hl * 3 + 1][cb];
                h_o += red[w][hl * 3 + 2][cb];
            }
            float gx_i = 1.f / (1.f + expf(-gv0));
            float fx_i = gx_i * (1.f - gx_i);
            float gx_f = 1.f / (1.f + expf(-gv1));
            float gx_o = 1.f / (1.f + expf(-gv3));
            float fx_o = gx_o * (1.f - gx_o);
            float gx_c = tanhf(gv2);
            float fx_c = 1.f - gx_c * gx_c;
            float g_c  = gx_i * gx_c;
            float g_ct = tanhf(g_c);
            float g_h  = gx_o * g_ct;

            float Bt = gx_f * c_reg;
            float Dt = gx_c * fx_i * h_i + gx_i * fx_c * h_g;
            float sech2 = 1.f - g_ct * g_ct;
            float Et = gx_o * sech2 * gx_f * c_reg;
            float Ft = gx_o * sech2 * Dt + fx_o * g_ct * h_o;

            float h_new = Et + Ft + ((t == 0) ? g_h : 0.f);
            float c_new = Bt + Dt + ((t == 0) ? g_c : 0.f);

            bool msk = (t < len_b);
            h_reg = msk ? h_new : h_reg;
            c_reg = msk ? c_new : c_reg;

            hbuf[((t + 1) & 1) * 65536 + blockIdx.x * 256 + tid] = h_reg;
            seq[(size_t)cb * (TT_ * HH_) + (size_t)t * HH_ + h0 + hl] = h_reg;
        }
        __threadfence();
        grid.sync();
    }
    if (tid < 256) hfin[(size_t)cb * HH_ + h0 + hl] = h_reg;
}

// ===========================================================================
extern "C" void kernel_launch(void* const* d_in, const int* in_sizes, int n_in,
                              void* d_out, int out_size, void* d_ws, size_t ws_size,
                              hipStream_t stream)
{
    const float* x   = (const float*)d_in[0];
    const int*   len = (const int*)d_in[1];
    const float* Wih = (const float*)d_in[2];
    const float* Whh = (const float*)d_in[3];
    float* out = (float*)d_out;

    float* hbase = (float*)d_ws;                       // 2*65536 f (512 KiB)
    float* gi    = hbase + 2 * 65536;                  // 512 MiB
    unsigned short* Ap = (unsigned short*)(gi + (size_t)32768 * 4096);  // 192 MiB
    unsigned short* Bp = Ap + (size_t)32768 * 3072;                     // 24 MiB

    const size_t need_full = (size_t)2 * 65536 * 4
                           + (size_t)32768 * 4096 * 4
                           + (size_t)32768 * 3072 * 2
                           + (size_t)4096 * 3072 * 2;
    const bool mfma_path = (ws_size >= need_full);

    if (mfma_path) {
        pack_x<<<dim3(32768), dim3(256), 0, stream>>>(x, Ap);
        pack_w<<<dim3(4096),  dim3(256), 0, stream>>>(Wih, Bp);
        gemm_bf16x3<<<dim3(32, 256), dim3(256), 0, stream>>>(Ap, Bp, gi);
    } else {
        gemm_nt_f32<<<dim3(256, 32), dim3(256), 0, stream>>>(
            x, 1024, 32768, Wih, gi, 4096);
    }

    float* seqp = out;
    float* hfin = out + (size_t)BB_ * TT_ * HH_;
    void* args[] = {(void*)&Whh, (void*)&gi, (void*)&len,
                    (void*)&hbase, (void*)&seqp, (void*)&hfin};
    hipLaunchCooperativeKernel((void*)lstm_persist, dim3(256), dim3(1024),
                               args, 0, stream);
}

// Round 3
// 13913.220 us; speedup vs baseline: 4.6695x; 4.6695x over previous
//
#include <hip/hip_runtime.h>
#include <math.h>

#define BB_  64
#define TT_  512
#define DD_  1024
#define HH_  1024

// ===========================================================================
// bf16 split helpers
// ===========================================================================
__device__ __forceinline__ unsigned short bf_rte(float f) {
    unsigned u = __float_as_uint(f);
    return (unsigned short)((u + 0x7FFFu + ((u >> 16) & 1u)) >> 16);
}
__device__ __forceinline__ void bf_split(float f, unsigned short& h,
                                         unsigned short& l) {
    unsigned u = __float_as_uint(f);
    unsigned r = (u + 0x7FFFu + ((u >> 16) & 1u)) >> 16;
    h = (unsigned short)r;
    l = bf_rte(f - __uint_as_float(r << 16));
}
// pack 8 consecutive f32 -> 8 bf16 (hi or lo part), as uint4
__device__ __forceinline__ uint4 pack8(float4 v0, float4 v1, bool lo) {
    float f[8] = {v0.x, v0.y, v0.z, v0.w, v1.x, v1.y, v1.z, v1.w};
    unsigned short s[8];
#pragma unroll
    for (int j = 0; j < 8; ++j) {
        unsigned short h, l;
        bf_split(f[j], h, l);
        s[j] = lo ? l : h;
    }
    uint4 r;
    r.x = (unsigned)s[0] | ((unsigned)s[1] << 16);
    r.y = (unsigned)s[2] | ((unsigned)s[3] << 16);
    r.z = (unsigned)s[4] | ((unsigned)s[5] << 16);
    r.w = (unsigned)s[6] | ((unsigned)s[7] << 16);
    return r;
}

// ===========================================================================
// Phase-1 GEMM, bf16x3 split done IN-KERNEL (no packed buffers needed):
//   gi[m][n] = sum_k x[m][k] * Wih[n][k],  m<32768, n<4096, k<1024
// Logical K = 3072 over 3 segments: (xh,Wh), (xh,Wl), (xl,Wh).
// 128x128 tile, BK=64, 4 waves, XOR-swizzled LDS. grid (32 n-tiles, 256 m).
// ===========================================================================
typedef short bf16x8 __attribute__((ext_vector_type(8)));
typedef float f32x4 __attribute__((ext_vector_type(4)));

__global__ __launch_bounds__(256)
void gemm_bf16x3(const float* __restrict__ X,    // [32768][1024]
                 const float* __restrict__ Wih,  // [4096][1024]
                 float* __restrict__ C)          // [32768][4096]
{
    __shared__ unsigned short As[128 * 64];
    __shared__ unsigned short Bs[128 * 64];
    const int tid = threadIdx.x;
    const size_t m0 = (size_t)blockIdx.y * 128;
    const size_t n0 = (size_t)blockIdx.x * 128;
    const int wave = tid >> 6, lane = tid & 63;
    const int wr = wave >> 1, wc = wave & 1;

    f32x4 acc[4][4];
#pragma unroll
    for (int i = 0; i < 4; ++i)
#pragma unroll
        for (int j = 0; j < 4; ++j)
#pragma unroll
            for (int r = 0; r < 4; ++r) acc[i][j][r] = 0.f;

    for (int ks = 0; ks < 48; ++ks) {
        const int seg = ks >> 4;           // 0,1,2
        const int kph = (ks & 15) << 6;    // physical k offset
        const bool aLo = (seg == 2);
        const bool bLo = (seg == 1);
        uint4 ua[4], ub[4];
#pragma unroll
        for (int c = 0; c < 4; ++c) {
            int chunk = tid + c * 256;     // [row 128][kc 8]
            int row = chunk >> 3, kc = chunk & 7;
            const float* ap = X + (m0 + row) * 1024 + kph + kc * 8;
            ua[c] = pack8(*(const float4*)ap, *(const float4*)(ap + 4), aLo);
            const float* bp = Wih + (n0 + row) * 1024 + kph + kc * 8;
            ub[c] = pack8(*(const float4*)bp, *(const float4*)(bp + 4), bLo);
        }
        __syncthreads();
#pragma unroll
        for (int c = 0; c < 4; ++c) {
            int chunk = tid + c * 256;
            int row = chunk >> 3, kc = chunk & 7;
            int sc = kc ^ (row & 7);
            *(uint4*)&As[row * 64 + sc * 8] = ua[c];
            *(uint4*)&Bs[row * 64 + sc * 8] = ub[c];
        }
        __syncthreads();
#pragma unroll
        for (int kk = 0; kk < 64; kk += 32) {
            bf16x8 af[4], bfv[4];
            const int ch = (kk >> 3) + (lane >> 4);
#pragma unroll
            for (int i = 0; i < 4; ++i) {
                int arow = wr * 64 + i * 16 + (lane & 15);
                af[i] = *(const bf16x8*)&As[arow * 64 + (ch ^ (arow & 7)) * 8];
                int brow = wc * 64 + i * 16 + (lane & 15);
                bfv[i] = *(const bf16x8*)&Bs[brow * 64 + (ch ^ (brow & 7)) * 8];
            }
#pragma unroll
            for (int i = 0; i < 4; ++i)
#pragma unroll
                for (int j = 0; j < 4; ++j)
                    acc[i][j] = __builtin_amdgcn_mfma_f32_16x16x32_bf16(
                        af[i], bfv[j], acc[i][j], 0, 0, 0);
        }
        __syncthreads();
    }
    // D: col = lane&15 (n), row = (lane>>4)*4 + reg (m)
#pragma unroll
    for (int i = 0; i < 4; ++i) {
        size_t mrow = m0 + wr * 64 + i * 16 + (lane >> 4) * 4;
#pragma unroll
        for (int j = 0; j < 4; ++j) {
            size_t ncol = n0 + wc * 64 + j * 16 + (lane & 15);
            float* cp = C + mrow * 4096 + ncol;
            cp[0]        = acc[i][j][0];
            cp[4096]     = acc[i][j][1];
            cp[2 * 4096] = acc[i][j][2];
            cp[3 * 4096] = acc[i][j][3];
        }
    }
}

// ===========================================================================
// fp32 fallback GEMM (R1-proven) — only if ws too small for full gi
// ===========================================================================
__global__ __launch_bounds__(256)
void gemm_nt_f32(const float* __restrict__ A, long lda, int M,
                 const float* __restrict__ Bw,
                 float* __restrict__ C, long ldc)
{
    __shared__ __align__(16) float As[16][132];
    __shared__ __align__(16) float Bs[16][132];
    const int tid = threadIdx.x;
    const long m0 = (long)blockIdx.x * 128;
    const long n0 = (long)blockIdx.y * 128;
    const int tx = tid & 15, ty = tid >> 4;
    const int sr = tid >> 2, sc = (tid & 3) << 2;
    float acc[8][8];
#pragma unroll
    for (int i = 0; i < 8; ++i)
#pragma unroll
        for (int j = 0; j < 8; ++j) acc[i][j] = 0.f;
    for (int k0 = 0; k0 < 1024; k0 += 16) {
#pragma unroll
        for (int rr = 0; rr < 2; ++rr) {
            long arow = m0 + sr + rr * 64;
            float4 v = make_float4(0.f, 0.f, 0.f, 0.f);
            if ((int)arow < M) v = *(const float4*)(A + arow * lda + k0 + sc);
            As[sc + 0][sr + rr * 64] = v.x; As[sc + 1][sr + rr * 64] = v.y;
            As[sc + 2][sr + rr * 64] = v.z; As[sc + 3][sr + rr * 64] = v.w;
            long bcol = n0 + sr + rr * 64;
            float4 w = *(const float4*)(Bw + bcol * 1024 + k0 + sc);
            Bs[sc + 0][sr + rr * 64] = w.x; Bs[sc + 1][sr + rr * 64] = w.y;
            Bs[sc + 2][sr + rr * 64] = w.z; Bs[sc + 3][sr + rr * 64] = w.w;
        }
        __syncthreads();
#pragma unroll
        for (int k = 0; k < 16; ++k) {
            float4 a0 = *(const float4*)&As[k][ty * 8];
            float4 a1 = *(const float4*)&As[k][ty * 8 + 4];
            float4 b0 = *(const float4*)&Bs[k][tx * 8];
            float4 b1 = *(const float4*)&Bs[k][tx * 8 + 4];
            float av[8] = {a0.x, a0.y, a0.z, a0.w, a1.x, a1.y, a1.z, a1.w};
            float bv[8] = {b0.x, b0.y, b0.z, b0.w, b1.x, b1.y, b1.z, b1.w};
#pragma unroll
            for (int i = 0; i < 8; ++i)
#pragma unroll
                for (int j = 0; j < 8; ++j) acc[i][j] += av[i] * bv[j];
        }
        __syncthreads();
    }
#pragma unroll
    for (int i = 0; i < 8; ++i) {
        long row = m0 + ty * 8 + i;
        if ((int)row < M) {
            *(float4*)(C + row * ldc + n0 + tx * 8) =
                make_float4(acc[i][0], acc[i][1], acc[i][2], acc[i][3]);
            *(float4*)(C + row * ldc + n0 + tx * 8 + 4) =
                make_float4(acc[i][4], acc[i][5], acc[i][6], acc[i][7]);
        }
    }
}

// ===========================================================================
// Recurrent step, per-launch. 256 blocks x 512 threads (8 waves, 2/SIMD).
// Block owns 4 h-cols. W slice (12 gate rows: q*4+hl, q in {i,g,o}) staged
// into LDS cooperatively each step; 8 waves split K 8-ways (lane = batch);
// LDS reduce; fused cell math in threads 0..255.
// ===========================================================================
__global__ __launch_bounds__(512)
void lstm_step(const float4* __restrict__ h_in,   // packed [256 k4][64 b]
               float4* __restrict__ h_out,
               float* __restrict__ cbuf,          // [1024 h][64 b]
               const float* __restrict__ gi,      // row b at gi + b*gstride
               long gstride,
               const float* __restrict__ Whh,     // [4096][1024]
               const int* __restrict__ lengths,
               float* __restrict__ seq,           // [64][512][1024]
               int t)
{
    __shared__ float Ws[12][1024];      // row r = q*4 + hl
    __shared__ float red[8][12][66];
    __shared__ float gix[4][4][68];     // [gate][hl][b]

    const int tid  = threadIdx.x;
    const int h0   = blockIdx.x << 2;
    const int wave = tid >> 6;
    const int lane = tid & 63;

    // ---- cooperative W-slice load into LDS (3072 float4s, 6 per thread) ----
#pragma unroll
    for (int it = 0; it < 6; ++it) {
        int i = tid + it * 512;          // float4 index into Ws
        int r = i >> 8;                  // 0..11
        int k4 = i & 255;
        int q = r >> 2, hl = r & 3;
        int grow = (q == 0) ? (h0 + hl) : (q == 1) ? (2048 + h0 + hl)
                                                   : (3072 + h0 + hl);
        *(float4*)&Ws[r][k4 * 4] =
            *(const float4*)(Whh + (size_t)grow * 1024 + k4 * 4);
    }

    // ---- gi prefetch (threads 0..255) ----
    if (tid < 256) {
        const int pb = tid >> 2, pg = tid & 3;
        const float4 gv = *reinterpret_cast<const float4*>(
            gi + (long)pb * gstride + pg * 1024 + h0);
        gix[pg][0][pb] = gv.x;
        gix[pg][1][pb] = gv.y;
        gix[pg][2][pb] = gv.z;
        gix[pg][3][pb] = gv.w;
    }
    __syncthreads();

    // ---- phase A: partial dots over this wave's 32 k4 (128 k) ----
    float acc[12];
#pragma unroll
    for (int r = 0; r < 12; ++r) acc[r] = 0.f;
    const int k4b = wave << 5;
    const float4* hq = h_in + (size_t)k4b * 64 + lane;
#pragma unroll 4
    for (int k4 = 0; k4 < 32; ++k4) {
        float4 hv = hq[(size_t)k4 * 64];
        const int kc = (k4b + k4) << 2;
#pragma unroll
        for (int r = 0; r < 12; ++r) {
            float4 wv = *(const float4*)&Ws[r][kc];
            acc[r] += hv.x * wv.x + hv.y * wv.y + hv.z * wv.z + hv.w * wv.w;
        }
    }
#pragma unroll
    for (int r = 0; r < 12; ++r) red[wave][r][lane] = acc[r];
    __syncthreads();

    // ---- phase B: reduce + cell (threads 0..255; b = tid>>2, hl = tid&3) ----
    if (tid < 256) {
        const int cb = tid >> 2;
        const int hl = tid & 3;
        float h_i = 0.f, h_g = 0.f, h_o = 0.f;
#pragma unroll
        for (int w = 0; w < 8; ++w) {
            h_i += red[w][0 + hl][cb];
            h_g += red[w][4 + hl][cb];
            h_o += red[w][8 + hl][cb];
        }
        float i_i = gix[0][hl][cb];
        float i_f = gix[1][hl][cb];
        float i_g = gix[2][hl][cb];
        float i_o = gix[3][hl][cb];

        float gx_i = 1.f / (1.f + expf(-i_i));
        float fx_i = gx_i * (1.f - gx_i);
        float gx_f = 1.f / (1.f + expf(-i_f));
        float gx_o = 1.f / (1.f + expf(-i_o));
        float fx_o = gx_o * (1.f - gx_o);
        float gx_c = tanhf(i_g);
        float fx_c = 1.f - gx_c * gx_c;
        float g_c  = gx_i * gx_c;
        float g_ct = tanhf(g_c);
        float g_h  = gx_o * g_ct;

        float c_old = cbuf[(size_t)(h0 + hl) * 64 + cb];
        float Bt = gx_f * c_old;
        float Dt = gx_c * fx_i * h_i + gx_i * fx_c * h_g;
        float sech2 = 1.f - g_ct * g_ct;
        float Et = gx_o * sech2 * gx_f * c_old;
        float Ft = gx_o * sech2 * Dt + fx_o * g_ct * h_o;

        float h_new = Et + Ft + ((t == 0) ? g_h : 0.f);
        float c_new = Bt + Dt + ((t == 0) ? g_c : 0.f);

        float hprev = ((const float*)h_in)[(size_t)blockIdx.x * 256 + tid];
        bool msk = (t < lengths[cb]);
        float h2 = msk ? h_new : hprev;
        float c2 = msk ? c_new : c_old;

        cbuf[(size_t)(h0 + hl) * 64 + cb] = c2;
        ((float*)h_out)[(size_t)blockIdx.x * 256 + tid] = h2;
        seq[(size_t)cb * (TT_ * HH_) + (size_t)t * HH_ + h0 + hl] = h2;
    }
}

// ===========================================================================
__global__ void zero_hc(float* __restrict__ hbuf0, float* __restrict__ cb)
{
    int i = blockIdx.x * 256 + threadIdx.x;   // grid 256 -> 65536 each
    hbuf0[i] = 0.f;
    cb[i]    = 0.f;
}

__global__ void h_final_k(const float* __restrict__ hbuf,
                          float* __restrict__ outf)
{
    int b = blockIdx.x;
    for (int h = threadIdx.x; h < 1024; h += 256)
        outf[(size_t)b * 1024 + h] =
            hbuf[(size_t)(h >> 2) * 256 + b * 4 + (h & 3)];
}

// ===========================================================================
extern "C" void kernel_launch(void* const* d_in, const int* in_sizes, int n_in,
                              void* d_out, int out_size, void* d_ws, size_t ws_size,
                              hipStream_t stream)
{
    const float* x   = (const float*)d_in[0];
    const int*   len = (const int*)d_in[1];
    const float* Wih = (const float*)d_in[2];
    const float* Whh = (const float*)d_in[3];
    float* out = (float*)d_out;

    float* hbase = (float*)d_ws;               // 2 x 65536 floats
    float* cb    = hbase + 2 * 65536;          // 65536 floats
    float* gi    = hbase + 3 * 65536;          // 512 MiB (or 1 MiB fallback)

    const size_t needA = (size_t)3 * 65536 * 4 + (size_t)32768 * 4096 * 4;
    const bool pathA = (ws_size >= needA);

    zero_hc<<<dim3(256), dim3(256), 0, stream>>>(hbase, cb);

    if (pathA) {
        gemm_bf16x3<<<dim3(32, 256), dim3(256), 0, stream>>>(x, Wih, gi);
    }

    for (int t = 0; t < 512; ++t) {
        const float* gstep;
        long gstride;
        if (pathA) {
            gstep = gi + (size_t)t * 4096;
            gstride = (long)TT_ * 4096;
        } else {
            gemm_nt_f32<<<dim3(1, 32), dim3(256), 0, stream>>>(
                x + (size_t)t * 1024, (long)TT_ * 1024, 64, Wih, gi, 4096);
            gstep = gi;
            gstride = 4096;
        }
        const float4* hin  = (const float4*)(hbase + (t & 1) * 65536);
        float4*       hout = (float4*)(hbase + ((t + 1) & 1) * 65536);
        lstm_step<<<dim3(256), dim3(512), 0, stream>>>(
            hin, hout, cb, gstep, gstride, Whh, len, out, t);
    }

    h_final_k<<<dim3(64), dim3(256), 0, stream>>>(
        hbase, out + (size_t)BB_ * TT_ * HH_);
}